// Round 2
// baseline (418.104 us; speedup 1.0000x reference)
//
#include <hip/hip_runtime.h>

// DWT2 Haar: x (16,64,256,256) fp32 -> out (16,256,128,128) fp32
// out[n][band*64+ch][i][j], band in {LL, H-row, H-col, HH}:
//   v0=x[2i,2j] v1=x[2i,2j+1] v2=x[2i+1,2j] v3=x[2i+1,2j+1]
//   out0=.5(v0+v1+v2+v3) out1=.5(v0+v1-v2-v3) out2=.5(v0-v1+v2-v3) out3=.5(v0-v1-v2+v3)
// Memory-bound: 1 GiB in + 1 GiB out -> ~340 us floor at 6.3 TB/s.
//
// 4 output cols per thread (8 input cols): every load/store is 16B dwordx4.
// Nontemporal hints on both streams (pure streaming, no reuse -> bypass L2).
// NOTE: __builtin_nontemporal_* requires a clang vector type, not HIP's
// struct float4 -> use ext_vector_type(4).

typedef float f32x4 __attribute__((ext_vector_type(4)));

__global__ __launch_bounds__(256) void DWT2_kernel(const float* __restrict__ x,
                                                   float* __restrict__ out) {
    constexpr int C = 64, H2 = 128, W2 = 128, W = 256;
    // idx bits: jo(5) | i(7) | ch(6) | nn(4);  total = 16*64*128*32 = 4,194,304
    int idx = blockIdx.x * 256 + threadIdx.x;
    int jo = idx & 31;          // output col quad: cols 4jo..4jo+3
    int t  = idx >> 5;
    int i  = t & 127;           // output row
    t >>= 7;
    int ch = t & 63;
    int nn = t >> 6;

    const float* p = x + (((size_t)(nn * C + ch) * 256 + 2 * i) * W + 8 * jo);
    // Row 2i: input cols 8jo..8jo+7 (two 16B loads), row 2i+1: same.
    f32x4 a0 = __builtin_nontemporal_load((const f32x4*)p);
    f32x4 a1 = __builtin_nontemporal_load((const f32x4*)(p + 4));
    f32x4 b0 = __builtin_nontemporal_load((const f32x4*)(p + W));
    f32x4 b1 = __builtin_nontemporal_load((const f32x4*)(p + W + 4));

    f32x4 o0, o1, o2, o3;
    {
        // output col 4jo+0  <- inputs (a0.x,a0.y | b0.x,b0.y)
        float s0 = a0.x + a0.y, d0 = a0.x - a0.y;
        float s1 = b0.x + b0.y, d1 = b0.x - b0.y;
        o0.x = 0.5f * (s0 + s1);
        o1.x = 0.5f * (s0 - s1);
        o2.x = 0.5f * (d0 + d1);
        o3.x = 0.5f * (d0 - d1);
        // output col 4jo+1  <- (a0.z,a0.w | b0.z,b0.w)
        s0 = a0.z + a0.w; d0 = a0.z - a0.w;
        s1 = b0.z + b0.w; d1 = b0.z - b0.w;
        o0.y = 0.5f * (s0 + s1);
        o1.y = 0.5f * (s0 - s1);
        o2.y = 0.5f * (d0 + d1);
        o3.y = 0.5f * (d0 - d1);
        // output col 4jo+2  <- (a1.x,a1.y | b1.x,b1.y)
        s0 = a1.x + a1.y; d0 = a1.x - a1.y;
        s1 = b1.x + b1.y; d1 = b1.x - b1.y;
        o0.z = 0.5f * (s0 + s1);
        o1.z = 0.5f * (s0 - s1);
        o2.z = 0.5f * (d0 + d1);
        o3.z = 0.5f * (d0 - d1);
        // output col 4jo+3  <- (a1.z,a1.w | b1.z,b1.w)
        s0 = a1.z + a1.w; d0 = a1.z - a1.w;
        s1 = b1.z + b1.w; d1 = b1.z - b1.w;
        o0.w = 0.5f * (s0 + s1);
        o1.w = 0.5f * (s0 - s1);
        o2.w = 0.5f * (d0 + d1);
        o3.w = 0.5f * (d0 - d1);
    }

    size_t ob = (((size_t)nn * 4 * C + ch) * H2 + i) * W2 + 4 * jo;
    constexpr size_t band = (size_t)C * H2 * W2;  // 1 Mi elements = 4 MiB
    __builtin_nontemporal_store(o0, (f32x4*)(out + ob));
    __builtin_nontemporal_store(o1, (f32x4*)(out + ob + band));
    __builtin_nontemporal_store(o2, (f32x4*)(out + ob + 2 * band));
    __builtin_nontemporal_store(o3, (f32x4*)(out + ob + 3 * band));
}

extern "C" void kernel_launch(void* const* d_in, const int* in_sizes, int n_in,
                              void* d_out, int out_size, void* d_ws, size_t ws_size,
                              hipStream_t stream) {
    const float* x = (const float*)d_in[0];
    float* out = (float*)d_out;
    // total threads = 16*64*128*32 = 4,194,304 -> 16384 blocks of 256
    DWT2_kernel<<<16384, 256, 0, stream>>>(x, out);
}